// Round 3
// baseline (1576.470 us; speedup 1.0000x reference)
//
#include <hip/hip_runtime.h>

typedef unsigned short u16;
typedef unsigned int u32;
typedef __bf16 bf16x8 __attribute__((ext_vector_type(8)));
typedef float f32x4 __attribute__((ext_vector_type(4)));
typedef u16 u16x4 __attribute__((ext_vector_type(4)));
typedef u16 u16x8 __attribute__((ext_vector_type(8)));

#define N_TW 1024
#define L_TOK 64
#define M1 (N_TW * L_TOK)
#define HCAP (2048 * 256)

__device__ __forceinline__ u16 f2bf(float f) {
  u32 u = __builtin_bit_cast(u32, f);
  u += 0x7fffu + ((u >> 16) & 1u);
  return (u16)(u >> 16);
}
__device__ __forceinline__ float bf2f(u16 b) {
  u32 u = ((u32)b) << 16;
  return __builtin_bit_cast(float, u);
}
__device__ __forceinline__ void gl_lds16(const void* g, void* l) {
  __builtin_amdgcn_global_load_lds((const __attribute__((address_space(1))) u32*)g,
                                   (__attribute__((address_space(3))) u32*)l, 16, 0, 0);
}
__device__ __forceinline__ float sigf(float x) { return 1.f / (1.f + __expf(-x)); }
__device__ __forceinline__ float tanh_(float x) { return 1.f - 2.f / (__expf(2.f * x) + 1.f); }

// ---------------- prep: fp32 -> bf16 weight conversion ----------------
__global__ __launch_bounds__(256) void k_f2bf(const float* __restrict__ s, u16* __restrict__ d, int n) {
  int i = (blockIdx.x * 256 + threadIdx.x) * 4;
  if (i < n) {
    float4 v = *(const float4*)(s + i);
    u16x4 o;
    o.x = f2bf(v.x); o.y = f2bf(v.y); o.z = f2bf(v.z); o.w = f2bf(v.w);
    *(u16x4*)(d + i) = o;
  }
}

__global__ __launch_bounds__(256) void k_bias(const float* __restrict__ a, const float* __restrict__ b,
                                              const float* __restrict__ c, const float* __restrict__ d,
                                              float* __restrict__ o) {
  int i = blockIdx.x * 256 + threadIdx.x;  // 0..2047
  o[i] = (i < 1024) ? (a[i] + b[i]) : (c[i - 1024] + d[i - 1024]);
}

// ---------------- embedding gather + bf16 convert ----------------
__global__ __launch_bounds__(256) void k_gather(const int* __restrict__ tok, const float* __restrict__ emb,
                                                u16* __restrict__ x) {
  long long t = (long long)blockIdx.x * 256 + threadIdx.x;
  long long base = t * 8;
  int row = (int)(base >> 9);
  int col = (int)(base & 511);
  long long src = (long long)tok[row] * 512 + col;
  float4 a = *(const float4*)(emb + src);
  float4 b = *(const float4*)(emb + src + 4);
  u16x8 o;
  o[0] = f2bf(a.x); o[1] = f2bf(a.y); o[2] = f2bf(a.z); o[3] = f2bf(a.w);
  o[4] = f2bf(b.x); o[5] = f2bf(b.y); o[6] = f2bf(b.z); o[7] = f2bf(b.w);
  *(u16x8*)(x + base) = o;
}

// ---------------- GEMM: xg[65536,2048] = X[65536,512] @ W[2048,512]^T + bias ----------------
// 128x128 tile, BK=64 (128B rows), T2 XOR-swizzle (both-sides), T1 XCD-chunked bid remap.
__global__ __launch_bounds__(256) void k_gemm_xg(const u16* __restrict__ X, const u16* __restrict__ W,
                                                 const float* __restrict__ bias, u16* __restrict__ XG) {
  __shared__ u16 Al[128 * 64];
  __shared__ u16 Bl[128 * 64];
  const int tid = threadIdx.x;
  const int wv = tid >> 6, lane = tid & 63;
  const int lr = lane & 15, lh = lane >> 4;
  const int bid = blockIdx.x;
  const int local = bid >> 3;
  const int bn = local & 15;                       // 16 col-blocks, fastest -> L2 reuse of X panel
  const int bm = (bid & 7) * 64 + (local >> 4);    // each XCD owns a contiguous 64-panel bm chunk
  f32x4 acc[2][8] = {};
  for (int kt = 0; kt < 8; ++kt) {
#pragma unroll
    for (int r = 0; r < 4; ++r) {
      int chunk = r * 4 + wv;
      int s = chunk * 1024 + lane * 16;
      int row = s >> 7;
      int kb = (s & 127) ^ ((row & 7) << 4);       // pre-swizzled global source (rule 21)
      gl_lds16(X + (size_t)(bm * 128 + row) * 512 + kt * 64 + (kb >> 1), (char*)Al + chunk * 1024);
      gl_lds16(W + (size_t)(bn * 128 + row) * 512 + kt * 64 + (kb >> 1), (char*)Bl + chunk * 1024);
    }
    __syncthreads();
#pragma unroll
    for (int ks = 0; ks < 2; ++ks) {
      int kbf = ks * 64 + lh * 16;
      int ra = wv * 32 + lr;
      int xa = kbf ^ ((ra & 7) << 4);
      bf16x8 a0 = *(const bf16x8*)((const char*)Al + ra * 128 + xa);
      bf16x8 a1 = *(const bf16x8*)((const char*)Al + (ra + 16) * 128 + xa);
#pragma unroll
      for (int nj = 0; nj < 8; ++nj) {
        int c = nj * 16 + lr;
        bf16x8 b = *(const bf16x8*)((const char*)Bl + c * 128 + (kbf ^ ((c & 7) << 4)));
        acc[0][nj] = __builtin_amdgcn_mfma_f32_16x16x32_bf16(a0, b, acc[0][nj], 0, 0, 0);
        acc[1][nj] = __builtin_amdgcn_mfma_f32_16x16x32_bf16(a1, b, acc[1][nj], 0, 0, 0);
      }
    }
    __syncthreads();
  }
#pragma unroll
  for (int mi = 0; mi < 2; ++mi)
#pragma unroll
    for (int nj = 0; nj < 8; ++nj) {
      int col = bn * 128 + nj * 16 + lr;
      float bv = bias[col];
#pragma unroll
      for (int r = 0; r < 4; ++r) {
        int row = bm * 128 + wv * 32 + mi * 16 + lh * 4 + r;
        XG[(long long)row * 2048 + col] = f2bf(acc[mi][nj][r] + bv);
      }
    }
}

// ---------------- image mean over 49 positions ----------------
__global__ __launch_bounds__(256) void k_imgmean(const float* __restrict__ img, u16* __restrict__ o) {
  int n = blockIdx.x;
  for (int j = 0; j < 2; ++j) {
    int col = threadIdx.x + j * 256;
    const float* p = img + (long long)n * 49 * 512 + col;
    float s = 0.f;
    for (int r = 0; r < 49; ++r) s += p[r * 512];
    o[(long long)n * 512 + col] = f2bf(s * (1.f / 49.f));
  }
}

// ---------------- image GEMM: O[1024,512] = A[1024,512] @ Wimg[512,512]^T + bias (fp32 out) ----------------
__global__ __launch_bounds__(256) void k_gemm_img(const u16* __restrict__ A, const u16* __restrict__ W,
                                                  const float* __restrict__ bias, float* __restrict__ O) {
  __shared__ u16 Al[128 * 32];
  __shared__ u16 Bl[128 * 32];
  const int tid = threadIdx.x;
  const int wv = tid >> 6, lane = tid & 63;
  const int bm = blockIdx.x, bn = blockIdx.y;  // 8 x 4
  f32x4 acc[2][8] = {};
  const int lr = lane & 15, lk = (lane >> 4) * 8;
  for (int kt = 0; kt < 16; ++kt) {
    for (int i = 0; i < 2; ++i) {
      int lin = (wv * 2 + i) * 64 + lane;
      int r = lin >> 2, kc = lin & 3;
      int k = kt * 32 + kc * 8;
      gl_lds16(A + (long long)(bm * 128 + r) * 512 + k, &Al[(wv * 2 + i) * 512]);
      gl_lds16(W + (long long)(bn * 128 + r) * 512 + k, &Bl[(wv * 2 + i) * 512]);
    }
    __syncthreads();
    bf16x8 a0 = *(const bf16x8*)&Al[(wv * 32 + lr) * 32 + lk];
    bf16x8 a1 = *(const bf16x8*)&Al[(wv * 32 + 16 + lr) * 32 + lk];
    for (int nj = 0; nj < 8; ++nj) {
      bf16x8 b = *(const bf16x8*)&Bl[(nj * 16 + lr) * 32 + lk];
      acc[0][nj] = __builtin_amdgcn_mfma_f32_16x16x32_bf16(a0, b, acc[0][nj], 0, 0, 0);
      acc[1][nj] = __builtin_amdgcn_mfma_f32_16x16x32_bf16(a1, b, acc[1][nj], 0, 0, 0);
    }
    __syncthreads();
  }
  const int lh = lane >> 4;
  for (int mi = 0; mi < 2; ++mi)
    for (int nj = 0; nj < 8; ++nj) {
      int col = bn * 128 + nj * 16 + lr;
      float bv = bias[col];
      for (int r = 0; r < 4; ++r) {
        int row = bm * 128 + wv * 32 + mi * 16 + lh * 4 + r;
        O[(long long)row * 512 + col] = acc[mi][nj][r] + bv;
      }
    }
}

// ---------------- persistent bidirectional LSTM: all 64 steps in one launch ----------------
// COOPERATIVE launch (co-residency guaranteed). 256 blocks. bm = bid&31 (64 tweet-dirs each),
// bn = bid>>5 (32-wide h slice). Group of 8 bn-blocks per bm exchanges h via global ping-pong +
// agent-scope atomic barrier. Block col c (0..127): wc=c>>6, gate=(c>>4)&3, hj=bn*32+wc*16+(c&15)
// -> each wave holds all 4 gates for its 16 hj -> cell update lane-local. c-state in registers.
__global__ __launch_bounds__(256) void k_lstm_persist(u16* __restrict__ hb,        // [2][2048][256]
                                                      const u16* __restrict__ Whh, // [2][1024][256]
                                                      const u16* __restrict__ XG,  // [65536][2048]
                                                      float* __restrict__ Hf,      // [2048][256]
                                                      int* __restrict__ barcnt, int* __restrict__ bargen) {
  extern __shared__ u16 lds[];
  u16* Bl = lds;           // 128 cols x 256 k (swizzled rows of 512B) = 64 KB
  u16* Al = lds + 32768;   // 64 rows x 256 k (swizzled) = 32 KB
  const int tid = threadIdx.x;
  const int wv = tid >> 6, lane = tid & 63;
  const int lr = lane & 15, lh = lane >> 4;
  const int wr = wv >> 1, wc = wv & 1;
  const int bid = blockIdx.x;
  const int bm = bid & 31, bn = bid >> 5;  // group members share XCD (bid%8 equal)
  const int dir = bm >> 4;
  const int m0 = bm * 64;
  const int hj = bn * 32 + wc * 16 + lr;

  // ---- stage B (Whh slice, gate-interleaved cols) once, swizzled ----
#pragma unroll
  for (int r = 0; r < 16; ++r) {
    int chunk = r * 4 + wv;
    int s = chunk * 1024 + lane * 16;
    int c = s >> 9;
    int kb = (s & 511) ^ ((c & 7) << 4);
    int gate = (c >> 4) & 3;
    int grow = gate * 256 + bn * 32 + ((c >> 6) << 4) + (c & 15);
    gl_lds16(Whh + (size_t)(dir * 1024 + grow) * 256 + (kb >> 1), (char*)Bl + chunk * 1024);
  }

  float cst[2][4] = {};
  f32x4 acc[2][4];
#pragma unroll 1
  for (int t = 0; t < 64; ++t) {
    const u16* hsrc = hb + (t & 1) * HCAP;
    u16* hdst = hb + ((t + 1) & 1) * HCAP;
    // ---- stage A = h_{t-1} for our 64 tweet-dirs, swizzled ----
#pragma unroll
    for (int r = 0; r < 8; ++r) {
      int chunk = r * 4 + wv;
      int s = chunk * 1024 + lane * 16;
      int row = s >> 9;
      int kb = (s & 511) ^ ((row & 7) << 4);
      gl_lds16(hsrc + (size_t)(m0 + row) * 256 + (kb >> 1), (char*)Al + chunk * 1024);
    }
    // ---- preload xg for this step (hides under MFMA) ----
    const int lt = dir ? (63 - t) : t;
    u16 xgv[2][4][4];
#pragma unroll
    for (int mi = 0; mi < 2; ++mi)
#pragma unroll
      for (int rr = 0; rr < 4; ++rr) {
        int trow = wr * 32 + mi * 16 + lh * 4 + rr;
        int n = (m0 + trow) & 1023;
        int base = ((n << 6) + lt) * 2048 + (dir << 10) + hj;
#pragma unroll
        for (int g = 0; g < 4; ++g) xgv[mi][rr][g] = XG[base + g * 256];
      }
#pragma unroll
    for (int mi = 0; mi < 2; ++mi)
#pragma unroll
      for (int nj = 0; nj < 4; ++nj) acc[mi][nj] = (f32x4){0.f, 0.f, 0.f, 0.f};
    __syncthreads();
    // ---- h @ Whh^T : 64 MFMA/wave ----
#pragma unroll
    for (int kt = 0; kt < 8; ++kt) {
      int kbf = kt * 64 + lh * 16;
      int ra = wr * 32 + lr;
      int xa = kbf ^ ((ra & 7) << 4);
      bf16x8 a0 = *(const bf16x8*)((const char*)Al + ra * 512 + xa);
      bf16x8 a1 = *(const bf16x8*)((const char*)Al + (ra + 16) * 512 + xa);
#pragma unroll
      for (int nj = 0; nj < 4; ++nj) {
        int c = wc * 64 + nj * 16 + lr;
        bf16x8 b = *(const bf16x8*)((const char*)Bl + c * 512 + (kbf ^ ((c & 7) << 4)));
        acc[0][nj] = __builtin_amdgcn_mfma_f32_16x16x32_bf16(a0, b, acc[0][nj], 0, 0, 0);
        acc[1][nj] = __builtin_amdgcn_mfma_f32_16x16x32_bf16(a1, b, acc[1][nj], 0, 0, 0);
      }
    }
    // ---- cell update (lane-local: gates = acc[mi][0..3][rr]) ----
#pragma unroll
    for (int mi = 0; mi < 2; ++mi)
#pragma unroll
      for (int rr = 0; rr < 4; ++rr) {
        int trow = wr * 32 + mi * 16 + lh * 4 + rr;
        int m = m0 + trow;
        float gi = acc[mi][0][rr] + bf2f(xgv[mi][rr][0]);
        float gf = acc[mi][1][rr] + bf2f(xgv[mi][rr][1]);
        float gg = acc[mi][2][rr] + bf2f(xgv[mi][rr][2]);
        float go = acc[mi][3][rr] + bf2f(xgv[mi][rr][3]);
        float cn = sigf(gf) * cst[mi][rr] + sigf(gi) * tanh_(gg);
        cst[mi][rr] = cn;
        float hn = sigf(go) * tanh_(cn);
        if (t < 63) hdst[m * 256 + hj] = f2bf(hn);
        else Hf[m * 256 + hj] = hn;
      }
    // ---- 8-block group barrier (agent-scope, monotonic generation) ----
    if (t < 63) {
      __syncthreads();  // drains vmcnt: all h-stores in L2 before arrive
      if (tid == 0) {
        int prev = __hip_atomic_fetch_add(&barcnt[bm], 1, __ATOMIC_ACQ_REL, __HIP_MEMORY_SCOPE_AGENT);
        if (prev == 8 * (t + 1) - 1)
          __hip_atomic_store(&bargen[bm], t + 1, __ATOMIC_RELEASE, __HIP_MEMORY_SCOPE_AGENT);
        while (__hip_atomic_load(&bargen[bm], __ATOMIC_ACQUIRE, __HIP_MEMORY_SCOPE_AGENT) < t + 1)
          __builtin_amdgcn_s_sleep(8);
      }
      __syncthreads();
    }
  }
}

// ---------------- attention fusion + mean over tweets (atomic accumulate) ----------------
__global__ __launch_bounds__(256) void k_fusion(const float* __restrict__ Hf, const float* __restrict__ IH,
                                                const float* __restrict__ WT, const float* __restrict__ WI,
                                                float* __restrict__ msum) {
  int wv = threadIdx.x >> 6, lane = threadIdx.x & 63;
  float facc[8] = {0.f, 0.f, 0.f, 0.f, 0.f, 0.f, 0.f, 0.f};
  for (int p = 0; p < 8; ++p) {
    int n = blockIdx.x * 32 + wv * 8 + p;
    float th[8], ih[8];
    float ts = 0.f, is = 0.f;
    for (int j = 0; j < 8; ++j) {
      int e = lane * 8 + j;
      float tv = (e < 256) ? Hf[(long long)n * 256 + e] : Hf[(long long)(1024 + n) * 256 + (e - 256)];
      float iv = IH[(long long)n * 512 + e];
      th[j] = tv; ih[j] = iv;
      ts += tv * WT[e];
      is += iv * WI[e];
    }
    for (int off = 32; off > 0; off >>= 1) {
      ts += __shfl_down(ts, off);
      is += __shfl_down(is, off);
    }
    ts = __shfl(ts, 0);
    is = __shfl(is, 0);
    float a0 = 1.f / (1.f + __expf(is - ts));
    float a1 = 1.f - a0;
    for (int j = 0; j < 8; ++j) facc[j] += a0 * th[j] + a1 * ih[j];
  }
  for (int j = 0; j < 8; ++j) atomicAdd(&msum[lane * 8 + j], facc[j]);
}

// ---------------- classifier MLP (single block) ----------------
__global__ __launch_bounds__(256) void k_cls(const float* __restrict__ msum, const float* __restrict__ Wc1,
                                             const float* __restrict__ bc1, const float* __restrict__ Wc2,
                                             const float* __restrict__ bc2, float* __restrict__ out) {
  __shared__ float mf[512];
  __shared__ float hdd[512];
  __shared__ float red[2][256];
  int tid = threadIdx.x;
  for (int j = tid; j < 512; j += 256) mf[j] = msum[j] * (1.f / 1024.f);
  __syncthreads();
  for (int j = tid; j < 512; j += 256) {
    const float* wr = Wc1 + (long long)j * 512;
    float s = bc1[j];
    for (int k = 0; k < 512; ++k) s += mf[k] * wr[k];
    hdd[j] = fmaxf(s, 0.f);
  }
  __syncthreads();
  float s0 = 0.f, s1 = 0.f;
  for (int k = tid; k < 512; k += 256) {
    s0 += hdd[k] * Wc2[k];
    s1 += hdd[k] * Wc2[512 + k];
  }
  red[0][tid] = s0;
  red[1][tid] = s1;
  __syncthreads();
  if (tid < 2) {
    float s = 0.f;
    for (int k = 0; k < 256; ++k) s += red[tid][k];
    out[tid] = s + bc2[tid];
  }
}

extern "C" void kernel_launch(void* const* d_in, const int* in_sizes, int n_in,
                              void* d_out, int out_size, void* d_ws, size_t ws_size,
                              hipStream_t stream) {
  const int* tokens = (const int*)d_in[0];
  const float* images = (const float*)d_in[1];
  const float* embed = (const float*)d_in[2];
  const float* Wih_f = (const float*)d_in[3];
  const float* Whh_f = (const float*)d_in[4];
  const float* bih_f = (const float*)d_in[5];
  const float* bhh_f = (const float*)d_in[6];
  const float* Wih_b = (const float*)d_in[7];
  const float* Whh_b = (const float*)d_in[8];
  const float* bih_b = (const float*)d_in[9];
  const float* bhh_b = (const float*)d_in[10];
  const float* Wimg = (const float*)d_in[11];
  const float* bimg = (const float*)d_in[12];
  const float* W_T = (const float*)d_in[13];
  const float* W_I = (const float*)d_in[14];
  const float* Wc1 = (const float*)d_in[15];
  const float* bc1 = (const float*)d_in[16];
  const float* Wc2 = (const float*)d_in[17];
  const float* bc2 = (const float*)d_in[18];
  float* out = (float*)d_out;

  char* ws = (char*)d_ws;
  size_t off = 0;
  auto alloc = [&](size_t bytes) -> void* {
    void* p = ws + off;
    off += (bytes + 255) & ~(size_t)255;
    return p;
  };
  u16* xbf = (u16*)alloc((size_t)M1 * 512 * 2);      // 64 MiB
  u16* xg = (u16*)alloc((size_t)M1 * 2048 * 2);      // 256 MiB
  u16* wih_bf = (u16*)alloc((size_t)2048 * 512 * 2);
  u16* whh_bf = (u16*)alloc((size_t)2 * 1024 * 256 * 2);
  u16* wimg_bf = (u16*)alloc((size_t)512 * 512 * 2);
  float* bias_a = (float*)alloc((size_t)2048 * 4);
  u16* hbuf = (u16*)alloc((size_t)2 * HCAP * 2);     // ping-pong h
  float* hf32 = (float*)alloc((size_t)2048 * 256 * 4);
  u16* im_bf = (u16*)alloc((size_t)1024 * 512 * 2);
  float* im_h = (float*)alloc((size_t)1024 * 512 * 4);
  float* msum = (float*)alloc((size_t)512 * 4);
  int* barcnt = (int*)alloc((size_t)64 * 4);  // [0:32)=count, [32:64)=generation (one slot!)
  int* bargen = barcnt + 32;

  hipMemsetAsync(hbuf, 0, (size_t)HCAP * 2, stream);  // h_{-1} = 0 (buffer 0)
  hipMemsetAsync(msum, 0, (size_t)512 * 4, stream);
  hipMemsetAsync(barcnt, 0, (size_t)64 * 4, stream);  // resets BOTH arrays every call

  k_f2bf<<<512, 256, 0, stream>>>(Wih_f, wih_bf, 524288);
  k_f2bf<<<512, 256, 0, stream>>>(Wih_b, wih_bf + 1024 * 512, 524288);
  k_f2bf<<<256, 256, 0, stream>>>(Whh_f, whh_bf, 262144);
  k_f2bf<<<256, 256, 0, stream>>>(Whh_b, whh_bf + 262144, 262144);
  k_f2bf<<<256, 256, 0, stream>>>(Wimg, wimg_bf, 262144);
  k_bias<<<8, 256, 0, stream>>>(bih_f, bhh_f, bih_b, bhh_b, bias_a);

  k_gather<<<16384, 256, 0, stream>>>(tokens, embed, xbf);
  k_gemm_xg<<<8192, 256, 0, stream>>>(xbf, wih_bf, bias_a, xg);

  k_imgmean<<<1024, 256, 0, stream>>>(images, im_bf);
  k_gemm_img<<<dim3(8, 4), 256, 0, stream>>>(im_bf, wimg_bf, bimg, im_h);

  hipFuncSetAttribute((const void*)k_lstm_persist, hipFuncAttributeMaxDynamicSharedMemorySize, 98304);
  {
    void* args[] = {(void*)&hbuf, (void*)&whh_bf, (void*)&xg, (void*)&hf32,
                    (void*)&barcnt, (void*)&bargen};
    hipLaunchCooperativeKernel((const void*)k_lstm_persist, dim3(256), dim3(256), args, 98304, stream);
  }

  k_fusion<<<32, 256, 0, stream>>>(hf32, im_h, W_T, W_I, msum);
  k_cls<<<1, 256, 0, stream>>>(msum, Wc1, bc1, Wc2, bc2, out);
}

// Round 4
// 1101.957 us; speedup vs baseline: 1.4306x; 1.4306x over previous
//
#include <hip/hip_runtime.h>

typedef unsigned short u16;
typedef unsigned int u32;
typedef __bf16 bf16x8 __attribute__((ext_vector_type(8)));
typedef float f32x4 __attribute__((ext_vector_type(4)));
typedef u16 u16x4 __attribute__((ext_vector_type(4)));
typedef u16 u16x8 __attribute__((ext_vector_type(8)));

#define N_TW 1024
#define L_TOK 64
#define M1 (N_TW * L_TOK)

__device__ __forceinline__ u16 f2bf(float f) {
  u32 u = __builtin_bit_cast(u32, f);
  u += 0x7fffu + ((u >> 16) & 1u);
  return (u16)(u >> 16);
}
__device__ __forceinline__ float bf2f(u16 b) {
  u32 u = ((u32)b) << 16;
  return __builtin_bit_cast(float, u);
}
__device__ __forceinline__ void gl_lds16(const void* g, void* l) {
  __builtin_amdgcn_global_load_lds((const __attribute__((address_space(1))) u32*)g,
                                   (__attribute__((address_space(3))) u32*)l, 16, 0, 0);
}
__device__ __forceinline__ float sigf(float x) { return 1.f / (1.f + __expf(-x)); }
__device__ __forceinline__ float tanh_(float x) { return 1.f - 2.f / (__expf(2.f * x) + 1.f); }

// ---------------- prep: fp32 -> bf16 weight conversion ----------------
__global__ __launch_bounds__(256) void k_f2bf(const float* __restrict__ s, u16* __restrict__ d, int n) {
  int i = (blockIdx.x * 256 + threadIdx.x) * 4;
  if (i < n) {
    float4 v = *(const float4*)(s + i);
    u16x4 o;
    o.x = f2bf(v.x); o.y = f2bf(v.y); o.z = f2bf(v.z); o.w = f2bf(v.w);
    *(u16x4*)(d + i) = o;
  }
}

__global__ __launch_bounds__(256) void k_bias(const float* __restrict__ a, const float* __restrict__ b,
                                              const float* __restrict__ c, const float* __restrict__ d,
                                              float* __restrict__ o) {
  int i = blockIdx.x * 256 + threadIdx.x;  // 0..2047
  o[i] = (i < 1024) ? (a[i] + b[i]) : (c[i - 1024] + d[i - 1024]);
}

// ---------------- Whh permute + pre-swizzle: WhhP[dir][phase16][col128][ke128] ----------------
// phase = kh*8+ch. col c: w=c>>5, l=(c&31)>>4, lr=c&15; ct=ch*2+l; s=ct>>2; g=ct&3; hj=w*64+s*16+lr.
// stored ke holds source k = kh*128 + (ke ^ ((c&7)<<3))  [inverse XOR so LDS linear-copy + XOR-read works]
__global__ __launch_bounds__(256) void k_prep_whh(const float* __restrict__ Wf, const float* __restrict__ Wb,
                                                  u16* __restrict__ P) {
  int e = blockIdx.x * 256 + threadIdx.x;  // 0..524287
  int dir = e >> 18;
  int r = e & 262143;
  int phase = r >> 14;
  int kh = phase >> 3, ch = phase & 7;
  int q = r & 16383;
  int c = q >> 7;
  int ke = q & 127;
  int ksrc = (kh << 7) + (ke ^ ((c & 7) << 3));
  int w = c >> 5, cw = c & 31, l = cw >> 4, lrr = cw & 15;
  int ct = ch * 2 + l, s = ct >> 2, g = ct & 3;
  int hj = w * 64 + s * 16 + lrr;
  const float* W = dir ? Wb : Wf;
  P[e] = f2bf(W[(g * 256 + hj) * 256 + ksrc]);
}

// ---------------- embedding gather + bf16 convert ----------------
__global__ __launch_bounds__(256) void k_gather(const int* __restrict__ tok, const float* __restrict__ emb,
                                                u16* __restrict__ x) {
  long long t = (long long)blockIdx.x * 256 + threadIdx.x;
  long long base = t * 8;
  int row = (int)(base >> 9);
  int col = (int)(base & 511);
  long long src = (long long)tok[row] * 512 + col;
  float4 a = *(const float4*)(emb + src);
  float4 b = *(const float4*)(emb + src + 4);
  u16x8 o;
  o[0] = f2bf(a.x); o[1] = f2bf(a.y); o[2] = f2bf(a.z); o[3] = f2bf(a.w);
  o[4] = f2bf(b.x); o[5] = f2bf(b.y); o[6] = f2bf(b.z); o[7] = f2bf(b.w);
  *(u16x8*)(x + base) = o;
}

// ---------------- GEMM: xg[65536,2048] = X[65536,512] @ W[2048,512]^T + bias ----------------
__global__ __launch_bounds__(256) void k_gemm_xg(const u16* __restrict__ X, const u16* __restrict__ W,
                                                 const float* __restrict__ bias, u16* __restrict__ XG) {
  __shared__ u16 Al[128 * 64];
  __shared__ u16 Bl[128 * 64];
  const int tid = threadIdx.x;
  const int wv = tid >> 6, lane = tid & 63;
  const int lr = lane & 15, lh = lane >> 4;
  const int bid = blockIdx.x;
  const int local = bid >> 3;
  const int bn = local & 15;
  const int bm = (bid & 7) * 64 + (local >> 4);
  f32x4 acc[2][8] = {};
  for (int kt = 0; kt < 8; ++kt) {
#pragma unroll
    for (int r = 0; r < 4; ++r) {
      int chunk = r * 4 + wv;
      int s = chunk * 1024 + lane * 16;
      int row = s >> 7;
      int kb = (s & 127) ^ ((row & 7) << 4);
      gl_lds16(X + (size_t)(bm * 128 + row) * 512 + kt * 64 + (kb >> 1), (char*)Al + chunk * 1024);
      gl_lds16(W + (size_t)(bn * 128 + row) * 512 + kt * 64 + (kb >> 1), (char*)Bl + chunk * 1024);
    }
    __syncthreads();
#pragma unroll
    for (int ks = 0; ks < 2; ++ks) {
      int kbf = ks * 64 + lh * 16;
      int ra = wv * 32 + lr;
      int xa = kbf ^ ((ra & 7) << 4);
      bf16x8 a0 = *(const bf16x8*)((const char*)Al + ra * 128 + xa);
      bf16x8 a1 = *(const bf16x8*)((const char*)Al + (ra + 16) * 128 + xa);
#pragma unroll
      for (int nj = 0; nj < 8; ++nj) {
        int c = nj * 16 + lr;
        bf16x8 b = *(const bf16x8*)((const char*)Bl + c * 128 + (kbf ^ ((c & 7) << 4)));
        acc[0][nj] = __builtin_amdgcn_mfma_f32_16x16x32_bf16(a0, b, acc[0][nj], 0, 0, 0);
        acc[1][nj] = __builtin_amdgcn_mfma_f32_16x16x32_bf16(a1, b, acc[1][nj], 0, 0, 0);
      }
    }
    __syncthreads();
  }
#pragma unroll
  for (int mi = 0; mi < 2; ++mi)
#pragma unroll
    for (int nj = 0; nj < 8; ++nj) {
      int col = bn * 128 + nj * 16 + lr;
      float bv = bias[col];
#pragma unroll
      for (int r = 0; r < 4; ++r) {
        int row = bm * 128 + wv * 32 + mi * 16 + lh * 4 + r;
        XG[(long long)row * 2048 + col] = f2bf(acc[mi][nj][r] + bv);
      }
    }
}

// ---------------- image mean over 49 positions ----------------
__global__ __launch_bounds__(256) void k_imgmean(const float* __restrict__ img, u16* __restrict__ o) {
  int n = blockIdx.x;
  for (int j = 0; j < 2; ++j) {
    int col = threadIdx.x + j * 256;
    const float* p = img + (long long)n * 49 * 512 + col;
    float s = 0.f;
    for (int r = 0; r < 49; ++r) s += p[r * 512];
    o[(long long)n * 512 + col] = f2bf(s * (1.f / 49.f));
  }
}

// ---------------- image GEMM ----------------
__global__ __launch_bounds__(256) void k_gemm_img(const u16* __restrict__ A, const u16* __restrict__ W,
                                                  const float* __restrict__ bias, float* __restrict__ O) {
  __shared__ u16 Al[128 * 32];
  __shared__ u16 Bl[128 * 32];
  const int tid = threadIdx.x;
  const int wv = tid >> 6, lane = tid & 63;
  const int bm = blockIdx.x, bn = blockIdx.y;
  f32x4 acc[2][8] = {};
  const int lr = lane & 15, lk = (lane >> 4) * 8;
  for (int kt = 0; kt < 16; ++kt) {
    for (int i = 0; i < 2; ++i) {
      int lin = (wv * 2 + i) * 64 + lane;
      int r = lin >> 2, kc = lin & 3;
      int k = kt * 32 + kc * 8;
      gl_lds16(A + (long long)(bm * 128 + r) * 512 + k, &Al[(wv * 2 + i) * 512]);
      gl_lds16(W + (long long)(bn * 128 + r) * 512 + k, &Bl[(wv * 2 + i) * 512]);
    }
    __syncthreads();
    bf16x8 a0 = *(const bf16x8*)&Al[(wv * 32 + lr) * 32 + lk];
    bf16x8 a1 = *(const bf16x8*)&Al[(wv * 32 + 16 + lr) * 32 + lk];
    for (int nj = 0; nj < 8; ++nj) {
      bf16x8 b = *(const bf16x8*)&Bl[(nj * 16 + lr) * 32 + lk];
      acc[0][nj] = __builtin_amdgcn_mfma_f32_16x16x32_bf16(a0, b, acc[0][nj], 0, 0, 0);
      acc[1][nj] = __builtin_amdgcn_mfma_f32_16x16x32_bf16(a1, b, acc[1][nj], 0, 0, 0);
    }
    __syncthreads();
  }
  const int lh = lane >> 4;
  for (int mi = 0; mi < 2; ++mi)
    for (int nj = 0; nj < 8; ++nj) {
      int col = bn * 128 + nj * 16 + lr;
      float bv = bias[col];
      for (int r = 0; r < 4; ++r) {
        int row = bm * 128 + wv * 32 + mi * 16 + lh * 4 + r;
        O[(long long)row * 512 + col] = acc[mi][nj][r] + bv;
      }
    }
}

// ---------------- LSTM: block-local recurrence, zero inter-block communication ----------------
// 128 blocks x 16 tweet-dirs. h ping-pongs through LDS (8KB), c in registers.
// Whh[dir] (512KB, pre-permuted WhhP) streamed from L2 each step: 16 phases x 32KB,
// 3-buffer rotation, counted vmcnt + raw barriers (T3/T4). xg tile staged via gl_lds too.
// LDS map (bytes): [0,96K) = 3 B-bufs; [96K? -> 98304,106496) = A(h) 8KB; [106496,139264) = xg 32KB.
__global__ __launch_bounds__(256) void k_lstm2(const u16* __restrict__ WhhP,
                                               const u16* __restrict__ XG,
                                               float* __restrict__ Hf) {
  extern __shared__ char lds[];
  u16* Ah = (u16*)(lds + 98304);
  u16* xgl = (u16*)(lds + 106496);
  const int tid = threadIdx.x;
  const int wv = tid >> 6, lane = tid & 63;
  const int lr = lane & 15, lh = lane >> 4;
  const int b = blockIdx.x;
  const int dir = b >> 6;
  const int m0 = b * 16;

  auto STAGE_W = [&](int ph, int bufi) {
    const u16* src = WhhP + (((size_t)dir * 16 + ph) << 14);
    u16* db = (u16*)(lds + bufi * 32768);
#pragma unroll
    for (int i = 0; i < 8; ++i)
      gl_lds16(src + (size_t)(i * 256 + tid) * 8, db + (i * 256 + wv * 64) * 8);
  };
  auto STAGE_XG = [&](int t_) {
    int lt = dir ? 63 - t_ : t_;
#pragma unroll
    for (int i = 0; i < 8; ++i) {
      int cc = i * 256 + tid;
      int g = cc >> 9, row = (cc >> 5) & 15, hj8 = cc & 31;
      int n = (m0 + row) & 1023;
      gl_lds16(XG + (size_t)((n << 6) + lt) * 2048 + (dir << 10) + (g << 8) + hj8 * 8,
               xgl + (i * 256 + wv * 64) * 8);
    }
  };

  // h_{-1} = 0
  u32* a32 = (u32*)(lds + 98304);
#pragma unroll
  for (int i = 0; i < 8; ++i) a32[tid * 8 + i] = 0;
  STAGE_W(0, 0);
  __syncthreads();

  float cst[16] = {};
  f32x4 acc[16];
  bf16x8 aF[4];

#pragma unroll 1
  for (int t = 0; t < 64; ++t) {
    STAGE_XG(t);  // FIFO: [ph0 (staged end of prev step)], xg, ph1, ph2, ...
#pragma unroll
    for (int ct = 0; ct < 16; ++ct) acc[ct] = (f32x4){0.f, 0.f, 0.f, 0.f};
#pragma unroll
    for (int p = 0; p < 16; ++p) {
      if (p < 15) STAGE_W(p + 1, (p + 1) % 3);
      if (p == 0) asm volatile("s_waitcnt vmcnt(16)" ::: "memory");
      else if (p < 15) asm volatile("s_waitcnt vmcnt(8)" ::: "memory");
      else asm volatile("s_waitcnt vmcnt(0)" ::: "memory");
      __builtin_amdgcn_s_barrier();
      asm volatile("" ::: "memory");
      const int kh = p >> 3, ch = p & 7;
      if (ch == 0) {
#pragma unroll
        for (int kf = 0; kf < 4; ++kf)
          aF[kf] = *(const bf16x8*)&Ah[lr * 256 + ((kh * 128 + kf * 32 + lh * 8) ^ ((lr & 7) << 3))];
      }
      const u16* Bb = (const u16*)(lds + (p % 3) * 32768);
#pragma unroll
      for (int kf = 0; kf < 4; ++kf) {
        int c0 = wv * 32 + lr;
        int c1 = c0 + 16;
        bf16x8 b0 = *(const bf16x8*)&Bb[c0 * 128 + ((kf * 32 + lh * 8) ^ ((c0 & 7) << 3))];
        bf16x8 b1 = *(const bf16x8*)&Bb[c1 * 128 + ((kf * 32 + lh * 8) ^ ((c1 & 7) << 3))];
        acc[ch * 2 + 0] = __builtin_amdgcn_mfma_f32_16x16x32_bf16(aF[kf], b0, acc[ch * 2 + 0], 0, 0, 0);
        acc[ch * 2 + 1] = __builtin_amdgcn_mfma_f32_16x16x32_bf16(aF[kf], b1, acc[ch * 2 + 1], 0, 0, 0);
      }
    }
    __syncthreads();                 // all waves done with bufs + A reads
    if (t < 63) STAGE_W(0, 0);       // prefetch next step's phase 0 (overlaps cell)
    // ---- cell update (lane-local gates) ----
#pragma unroll
    for (int s = 0; s < 4; ++s)
#pragma unroll
      for (int rr = 0; rr < 4; ++rr) {
        int row = lh * 4 + rr;
        int hjv = wv * 64 + s * 16 + lr;
        float gi = acc[s * 4 + 0][rr] + bf2f(xgl[row * 256 + hjv]);
        float gf = acc[s * 4 + 1][rr] + bf2f(xgl[4096 + row * 256 + hjv]);
        float gg = acc[s * 4 + 2][rr] + bf2f(xgl[8192 + row * 256 + hjv]);
        float go = acc[s * 4 + 3][rr] + bf2f(xgl[12288 + row * 256 + hjv]);
        float cn = sigf(gf) * cst[s * 4 + rr] + sigf(gi) * tanh_(gg);
        cst[s * 4 + rr] = cn;
        float hn = sigf(go) * tanh_(cn);
        if (t < 63) Ah[row * 256 + (hjv ^ ((row & 7) << 3))] = f2bf(hn);
        else Hf[(size_t)(m0 + row) * 256 + hjv] = hn;
      }
    __syncthreads();                 // h visible before next step's reads / xg restage
  }
}

// ---------------- attention fusion + mean over tweets ----------------
__global__ __launch_bounds__(256) void k_fusion(const float* __restrict__ Hf, const float* __restrict__ IH,
                                                const float* __restrict__ WT, const float* __restrict__ WI,
                                                float* __restrict__ msum) {
  int wv = threadIdx.x >> 6, lane = threadIdx.x & 63;
  float facc[8] = {0.f, 0.f, 0.f, 0.f, 0.f, 0.f, 0.f, 0.f};
  for (int p = 0; p < 8; ++p) {
    int n = blockIdx.x * 32 + wv * 8 + p;
    float th[8], ih[8];
    float ts = 0.f, is = 0.f;
    for (int j = 0; j < 8; ++j) {
      int e = lane * 8 + j;
      float tv = (e < 256) ? Hf[(long long)n * 256 + e] : Hf[(long long)(1024 + n) * 256 + (e - 256)];
      float iv = IH[(long long)n * 512 + e];
      th[j] = tv; ih[j] = iv;
      ts += tv * WT[e];
      is += iv * WI[e];
    }
    for (int off = 32; off > 0; off >>= 1) {
      ts += __shfl_down(ts, off);
      is += __shfl_down(is, off);
    }
    ts = __shfl(ts, 0);
    is = __shfl(is, 0);
    float a0 = 1.f / (1.f + __expf(is - ts));
    float a1 = 1.f - a0;
    for (int j = 0; j < 8; ++j) facc[j] += a0 * th[j] + a1 * ih[j];
  }
  for (int j = 0; j < 8; ++j) atomicAdd(&msum[lane * 8 + j], facc[j]);
}

// ---------------- classifier MLP ----------------
__global__ __launch_bounds__(256) void k_cls(const float* __restrict__ msum, const float* __restrict__ Wc1,
                                             const float* __restrict__ bc1, const float* __restrict__ Wc2,
                                             const float* __restrict__ bc2, float* __restrict__ out) {
  __shared__ float mf[512];
  __shared__ float hdd[512];
  __shared__ float red[2][256];
  int tid = threadIdx.x;
  for (int j = tid; j < 512; j += 256) mf[j] = msum[j] * (1.f / 1024.f);
  __syncthreads();
  for (int j = tid; j < 512; j += 256) {
    const float* wr = Wc1 + (long long)j * 512;
    float s = bc1[j];
    for (int k = 0; k < 512; ++k) s += mf[k] * wr[k];
    hdd[j] = fmaxf(s, 0.f);
  }
  __syncthreads();
  float s0 = 0.f, s1 = 0.f;
  for (int k = tid; k < 512; k += 256) {
    s0 += hdd[k] * Wc2[k];
    s1 += hdd[k] * Wc2[512 + k];
  }
  red[0][tid] = s0;
  red[1][tid] = s1;
  __syncthreads();
  if (tid < 2) {
    float s = 0.f;
    for (int k = 0; k < 256; ++k) s += red[tid][k];
    out[tid] = s + bc2[tid];
  }
}

extern "C" void kernel_launch(void* const* d_in, const int* in_sizes, int n_in,
                              void* d_out, int out_size, void* d_ws, size_t ws_size,
                              hipStream_t stream) {
  const int* tokens = (const int*)d_in[0];
  const float* images = (const float*)d_in[1];
  const float* embed = (const float*)d_in[2];
  const float* Wih_f = (const float*)d_in[3];
  const float* Whh_f = (const float*)d_in[4];
  const float* bih_f = (const float*)d_in[5];
  const float* bhh_f = (const float*)d_in[6];
  const float* Wih_b = (const float*)d_in[7];
  const float* Whh_b = (const float*)d_in[8];
  const float* bih_b = (const float*)d_in[9];
  const float* bhh_b = (const float*)d_in[10];
  const float* Wimg = (const float*)d_in[11];
  const float* bimg = (const float*)d_in[12];
  const float* W_T = (const float*)d_in[13];
  const float* W_I = (const float*)d_in[14];
  const float* Wc1 = (const float*)d_in[15];
  const float* bc1 = (const float*)d_in[16];
  const float* Wc2 = (const float*)d_in[17];
  const float* bc2 = (const float*)d_in[18];
  float* out = (float*)d_out;

  char* ws = (char*)d_ws;
  size_t off = 0;
  auto alloc = [&](size_t bytes) -> void* {
    void* p = ws + off;
    off += (bytes + 255) & ~(size_t)255;
    return p;
  };
  u16* xbf = (u16*)alloc((size_t)M1 * 512 * 2);       // 64 MiB
  u16* xg = (u16*)alloc((size_t)M1 * 2048 * 2);       // 256 MiB
  u16* wih_bf = (u16*)alloc((size_t)2048 * 512 * 2);
  u16* whhP = (u16*)alloc((size_t)2 * 262144 * 2);    // 1 MiB permuted Whh
  u16* wimg_bf = (u16*)alloc((size_t)512 * 512 * 2);
  float* bias_a = (float*)alloc((size_t)2048 * 4);
  float* hf32 = (float*)alloc((size_t)2048 * 256 * 4);
  u16* im_bf = (u16*)alloc((size_t)1024 * 512 * 2);
  float* im_h = (float*)alloc((size_t)1024 * 512 * 4);
  float* msum = (float*)alloc((size_t)512 * 4);

  hipMemsetAsync(msum, 0, (size_t)512 * 4, stream);

  k_f2bf<<<512, 256, 0, stream>>>(Wih_f, wih_bf, 524288);
  k_f2bf<<<512, 256, 0, stream>>>(Wih_b, wih_bf + 1024 * 512, 524288);
  k_f2bf<<<256, 256, 0, stream>>>(Wimg, wimg_bf, 262144);
  k_prep_whh<<<2048, 256, 0, stream>>>(Whh_f, Whh_b, whhP);
  k_bias<<<8, 256, 0, stream>>>(bih_f, bhh_f, bih_b, bhh_b, bias_a);

  k_gather<<<16384, 256, 0, stream>>>(tokens, embed, xbf);
  k_gemm_xg<<<8192, 256, 0, stream>>>(xbf, wih_bf, bias_a, xg);

  k_imgmean<<<1024, 256, 0, stream>>>(images, im_bf);
  k_gemm_img<<<dim3(8, 4), 256, 0, stream>>>(im_bf, wimg_bf, bimg, im_h);

  hipFuncSetAttribute((const void*)k_lstm2, hipFuncAttributeMaxDynamicSharedMemorySize, 139264);
  k_lstm2<<<128, 256, 139264, stream>>>(whhP, xg, hf32);

  k_fusion<<<32, 256, 0, stream>>>(hf32, im_h, W_T, W_I, msum);
  k_cls<<<1, 256, 0, stream>>>(msum, Wc1, bc1, Wc2, bc2, out);
}